// Round 1
// 271.829 us; speedup vs baseline: 1.2537x; 1.2537x over previous
//
#include <hip/hip_runtime.h>
#include <hip/hip_fp16.h>
#include <hip/hip_fp8.h>
#include <math.h>

#define N_NODES 50000
#define N_EDGES 1200000
#define N_GRAPHS 128
#define D_IN 32
#define D_H 64
#define D_OUT 10
#define ELL_CAP 64

#define EPS 1e-7f
#define MAX_NORM (1.0f - 1e-5f)
// atanh(MAX_NORM): logmap0(proj(expmap0(m))) == m * min(1, TCLIP/||m||)
#define TCLIP 6.1030335f
#define T8SCALE 16.0f            // fp8 table pre-scale (folded into mean div)

// ---- atomic-free ELL build: counting partition ----
#define HB 512                               // partition blocks (chunks)
#define CHUNK ((N_EDGES + HB - 1) / HB)      // 2344 edges per chunk
#define NBUCK ((N_NODES + 63) / 64)          // 782 buckets of 64 nodes

typedef _Float16 half8 __attribute__((ext_vector_type(8)));
typedef float float4v __attribute__((ext_vector_type(4)));

// ---------------- wave helpers ----------------

__device__ __forceinline__ float wave_reduce_sum(float v) {
    #pragma unroll
    for (int off = 32; off > 0; off >>= 1)
        v += __shfl_xor(v, off, 64);
    return v;
}

__device__ __forceinline__ float reduce32(float v) {
    #pragma unroll
    for (int off = 16; off > 0; off >>= 1)
        v += __shfl_xor(v, off, 64);
    return v;
}

// logmap0(proj(expmap0(m))) collapsed to a norm clip (one reduction).
__device__ __forceinline__ float epl_clip64(float m) {
    float n = sqrtf(wave_reduce_sum(m * m));
    float sc = (n > TCLIP) ? (TCLIP / n) : 1.0f;
    return m * sc;
}

// two packed OCP e4m3 bytes -> two floats (gfx950 HW cvt)
__device__ __forceinline__ float2 fp8x2_to_f2(ushort v) {
    __hip_fp8_e4m3 a, b;
    a.__x = (__hip_fp8_storage_t)(v & 0xff);
    b.__x = (__hip_fp8_storage_t)(v >> 8);
    return make_float2((float)a, (float)b);
}

// ---------------- kernels ----------------

// Partition pass: blocks [0,HB) bucket-sort their edge chunk locally
// (LDS histogram + scan + LDS-atomic rank; all global writes coalesced
// into the block's own window -> full write combining, NO global atomics).
// Blocks [HB..): tangent0 = fp16(clip(x)) (unchanged u0 computation).
__global__ void partsort_kernel(const int* __restrict__ src, const int* __restrict__ dst,
                                unsigned* __restrict__ sorted, int* __restrict__ rowOffs,
                                const float* __restrict__ x, __half* __restrict__ u0) {
    __shared__ int hist[1024];   // NBUCK=782 padded to 4*256
    __shared__ int wsum[256];
    if (blockIdx.x >= HB) {
        int gid = (blockIdx.x - HB) * 256 + threadIdx.x;
        int node = gid >> 6;
        int lane = gid & 63;
        if (node >= N_NODES) return;
        float m = (lane < D_IN) ? x[node * D_IN + lane] : 0.0f;
        float t = epl_clip64(m);
        if (lane < D_IN) u0[node * D_IN + lane] = __float2half(t);
        return;
    }
    int i = blockIdx.x;
    int e0 = i * CHUNK;
    int e1 = min(e0 + CHUNK, N_EDGES);

    for (int t = threadIdx.x; t < 1024; t += 256) hist[t] = 0;
    __syncthreads();
    // pass 1: bucket histogram (LDS atomics only)
    for (int e = e0 + threadIdx.x; e < e1; e += 256) {
        int d = dst[e];
        d = min(max(d, 0), N_NODES - 1);
        atomicAdd(&hist[d >> 6], 1);
    }
    __syncthreads();
    // exclusive scan of hist[0..1023]: 4 elems/thread + block scan of sums
    int t = threadIdx.x;
    int a0 = hist[4 * t], a1 = hist[4 * t + 1], a2 = hist[4 * t + 2], a3 = hist[4 * t + 3];
    int s01 = a0 + a1;
    int s = s01 + a2 + a3;
    wsum[t] = s;
    __syncthreads();
    for (int off = 1; off < 256; off <<= 1) {
        int v = (t >= off) ? wsum[t - off] : 0;
        __syncthreads();
        wsum[t] += v;
        __syncthreads();
    }
    int base = wsum[t] - s;      // exclusive prefix of this thread's 4
    hist[4 * t]     = base;
    hist[4 * t + 1] = base + a0;
    hist[4 * t + 2] = base + s01;
    hist[4 * t + 3] = base + s01 + a2;
    __syncthreads();
    // publish per-(chunk,bucket) offsets; row-major -> coalesced writes.
    // hist[NBUCK] == chunk length (buckets >= NBUCK are empty).
    for (int jj = threadIdx.x; jj <= NBUCK; jj += 256)
        rowOffs[i * (NBUCK + 1) + jj] = hist[jj];
    __syncthreads();
    // pass 2: rank via LDS atomic on the scanned cursors, write packed edge
    // into this block's own CHUNK-sized window (stays in one L2, combines).
    for (int e = e0 + threadIdx.x; e < e1; e += 256) {
        int s_ = src[e];
        int d  = dst[e];
        s_ = min(max(s_, 0), N_NODES - 1);
        d  = min(max(d,  0), N_NODES - 1);
        int pos = atomicAdd(&hist[d >> 6], 1);
        sorted[(size_t)i * CHUNK + pos] = ((unsigned)d << 16) | (unsigned)s_;
    }
}

// ELL build: one block per 64-node bucket. Gathers this bucket's runs from
// all HB chunk windows; ranks with LDS atomics; ELL writes land in the
// block's own contiguous 16KB region (perfect write combining). Exact deg
// falls out of the counters -> no deg memset needed.
__global__ void ellbuild_kernel(const unsigned* __restrict__ sorted, const int* __restrict__ rowOffs,
                                int* __restrict__ deg, ushort* __restrict__ ell) {
    __shared__ int cnt[64];
    int j = blockIdx.x;
    if (threadIdx.x < 64) cnt[threadIdx.x] = 0;
    __syncthreads();
    for (int i = threadIdx.x; i < HB; i += 256) {
        int b0 = rowOffs[i * (NBUCK + 1) + j];
        int b1 = rowOffs[i * (NBUCK + 1) + j + 1];
        const unsigned* sp = sorted + (size_t)i * CHUNK;
        for (int e = b0; e < b1; ++e) {
            unsigned p = sp[e];
            int dl = (int)(p >> 16) & 63;
            int pos = atomicAdd(&cnt[dl], 1);
            if (pos < ELL_CAP)
                ell[(size_t)((j << 6) + dl) * ELL_CAP + pos] = (ushort)(p & 0xffffu);
        }
    }
    __syncthreads();
    int node = (j << 6) + threadIdx.x;
    if (threadIdx.x < 64 && node < N_NODES) deg[node] = cnt[threadIdx.x];
}

// Repack W (f32 [K,64]) into B-fragment order for mfma_f32_16x16x32_f16.
template <int K>
__global__ void repack_kernel(const float* __restrict__ W, __half* __restrict__ Whf) {
    const int NF = K / 32;
    int idx = blockIdx.x * 256 + threadIdx.x;
    if (idx >= 4 * NF * 64 * 8) return;
    int j = idx & 7;
    int lane = (idx >> 3) & 63;
    int f = (idx >> 9) % NF;
    int jb = (idx >> 9) / NF;
    int k = f * 32 + ((lane >> 4) * 8) + j;
    int n = jb * 16 + (lane & 15);
    Whf[idx] = __float2half(W[k * 64 + n]);
}

// LAYER 1 pass A: gather-mean of u0 rows (32-dim fp16, 64B = 1 line/edge,
// 3.2MB L2-resident). Quad-per-edge, 4 edges per wave-load.
__global__ void meangather_kernel(const __half* __restrict__ u0, const int* __restrict__ deg,
                                  const ushort* __restrict__ ell, __half* __restrict__ m0) {
    int widx = threadIdx.x >> 6;
    int lane = threadIdx.x & 63;
    int node = blockIdx.x * 4 + widx;
    if (node >= N_NODES) return;
    int quad = lane >> 4;
    int p = lane & 15;                 // dim pair 2p, 2p+1
    int dt = deg[node];
    int d = min(dt, ELL_CAP);
    int id = (lane < d) ? (int)ell[node * ELL_CAP + lane] : 0;
    const __half2* u2 = (const __half2*)u0;   // row stride 16 half2

    float ax = 0.f, ay = 0.f;
    int e = 0;
    for (; e + 16 <= d; e += 16) {     // 16 edges, 4 loads in flight
        int sA0 = __shfl(id, e,      64), sB0 = __shfl(id, e + 1,  64);
        int sC0 = __shfl(id, e + 2,  64), sD0 = __shfl(id, e + 3,  64);
        int sA1 = __shfl(id, e + 4,  64), sB1 = __shfl(id, e + 5,  64);
        int sC1 = __shfl(id, e + 6,  64), sD1 = __shfl(id, e + 7,  64);
        int sA2 = __shfl(id, e + 8,  64), sB2 = __shfl(id, e + 9,  64);
        int sC2 = __shfl(id, e + 10, 64), sD2 = __shfl(id, e + 11, 64);
        int sA3 = __shfl(id, e + 12, 64), sB3 = __shfl(id, e + 13, 64);
        int sC3 = __shfl(id, e + 14, 64), sD3 = __shfl(id, e + 15, 64);
        int t0 = (quad & 1) ? sB0 : sA0, v0 = (quad & 1) ? sD0 : sC0;
        int t1 = (quad & 1) ? sB1 : sA1, v1 = (quad & 1) ? sD1 : sC1;
        int t2_ = (quad & 1) ? sB2 : sA2, v2 = (quad & 1) ? sD2 : sC2;
        int t3 = (quad & 1) ? sB3 : sA3, v3 = (quad & 1) ? sD3 : sC3;
        int s0 = (quad & 2) ? v0 : t0;
        int s1 = (quad & 2) ? v1 : t1;
        int s2 = (quad & 2) ? v2 : t2_;
        int s3 = (quad & 2) ? v3 : t3;
        float2 f0 = __half22float2(u2[s0 * 16 + p]);
        float2 f1 = __half22float2(u2[s1 * 16 + p]);
        float2 f2 = __half22float2(u2[s2 * 16 + p]);
        float2 f3 = __half22float2(u2[s3 * 16 + p]);
        ax += (f0.x + f1.x) + (f2.x + f3.x);
        ay += (f0.y + f1.y) + (f2.y + f3.y);
    }
    if (e + 4 <= d) {
        do {
            int sA = __shfl(id, e, 64), sB = __shfl(id, e + 1, 64);
            int sC = __shfl(id, e + 2, 64), sD = __shfl(id, e + 3, 64);
            int tt = (quad & 1) ? sB : sA, vv = (quad & 1) ? sD : sC;
            int s = (quad & 2) ? vv : tt;
            float2 f = __half22float2(u2[s * 16 + p]);
            ax += f.x; ay += f.y;
            e += 4;
        } while (e + 4 <= d);
    }
    for (; e < d; ++e) {
        int s = __shfl(id, e, 64);
        if (quad == 0) {
            float2 f = __half22float2(u2[s * 16 + p]);
            ax += f.x; ay += f.y;
        }
    }
    ax += __shfl_xor(ax, 16, 64); ax += __shfl_xor(ax, 32, 64);
    ay += __shfl_xor(ay, 16, 64); ay += __shfl_xor(ay, 32, 64);

    float inv = 1.0f / fmaxf((float)dt, 1.0f);
    if (quad == 0)
        ((__half2*)m0)[node * 16 + p] = __floats2half2_rn(ax * inv, ay * inv);
}

// LAYER 1 pass B: u1 = clip(lrelu(m0@W1 + b1)), deg==0 -> 0.
__global__ void gemmepi_kernel(const __half* __restrict__ m0, const __half* __restrict__ Whf,
                               const float* __restrict__ b, const int* __restrict__ deg,
                               __half* __restrict__ uout) {
    int gw = blockIdx.x * 4 + (threadIdx.x >> 6);
    int lane = threadIdx.x & 63;
    int node0 = gw * 16;
    if (node0 >= N_NODES) return;
    int m = lane & 15, quad = lane >> 4;

    half8 a = *(const half8*)(m0 + (size_t)(node0 + m) * 32 + quad * 8);
    float h[4][4];   // [jb][r]
    #pragma unroll
    for (int jb = 0; jb < 4; ++jb) {
        float4v acc = {0.f, 0.f, 0.f, 0.f};
        half8 bb = ((const half8*)Whf)[jb * 64 + lane];
        acc = __builtin_amdgcn_mfma_f32_16x16x32_f16(a, bb, acc, 0, 0, 0);
        float bias = b[jb * 16 + m];
        #pragma unroll
        for (int r = 0; r < 4; ++r) h[jb][r] = acc[r] + bias;
    }
    #pragma unroll
    for (int r = 0; r < 4; ++r) {
        int node = node0 + quad * 4 + r;   // C/D: col=lane&15, row=quad*4+reg
        int dt = deg[node];
        float nr = 0.f;
        #pragma unroll
        for (int jb = 0; jb < 4; ++jb) {
            float v = (dt == 0) ? 0.f : h[jb][r];
            v = (v >= 0.f) ? v : 0.2f * v;   // leaky_relu (layer 1)
            h[jb][r] = v;
            nr += v * v;
        }
        nr += __shfl_xor(nr, 1, 64); nr += __shfl_xor(nr, 2, 64);
        nr += __shfl_xor(nr, 4, 64); nr += __shfl_xor(nr, 8, 64);
        float n = sqrtf(nr);
        float sc = (n > TCLIP) ? (TCLIP / n) : 1.0f;
        #pragma unroll
        for (int jb = 0; jb < 4; ++jb)
            uout[node * 64 + jb * 16 + m] = __float2half(h[jb][r] * sc);
    }
}

// t[N,64] fp8 e4m3 (x16 scale) = u[N,K] fp16 @ W + b via MFMA (layers 2,3).
// fp8 rows are 64B = ONE line per edge-gather (R16: line-request-rate model).
template <int K>
__global__ void gemm_kernel(const __half* __restrict__ u, const __half* __restrict__ Whf,
                            const float* __restrict__ b, __hip_fp8_e4m3* __restrict__ t8) {
    const int NF = K / 32;
    int gw = blockIdx.x * 4 + (threadIdx.x >> 6);
    int lane = threadIdx.x & 63;
    int jb = gw & 3;
    int tile = gw >> 2;
    int node0 = tile * 16;
    if (node0 >= N_NODES) return;
    int m = lane & 15, quad = lane >> 4;

    float4v acc = {0.f, 0.f, 0.f, 0.f};
    const half8* bfr = (const half8*)Whf + (size_t)(jb * NF) * 64 + lane;
    #pragma unroll
    for (int f = 0; f < NF; ++f) {
        half8 a = *(const half8*)(u + (size_t)(node0 + m) * K + f * 32 + quad * 8);
        half8 bb = bfr[f * 64];
        acc = __builtin_amdgcn_mfma_f32_16x16x32_f16(a, bb, acc, 0, 0, 0);
    }
    int j = jb * 16 + m;
    float bias = b[j];
    #pragma unroll
    for (int r = 0; r < 4; ++r) {
        int node = node0 + quad * 4 + r;
        t8[node * 64 + j] = __hip_fp8_e4m3((acc[r] + bias) * T8SCALE);
    }
}

// Gather-mean over ELL (fp8 rows, 64B = 1 line/edge; dual-edge pattern,
// 8 loads in flight) -> act -> norm-clip -> fp16 store, or (POOL) block
// LDS combine + 1 atomic burst per block. (layers 2,3)
template <int ACT, int POOL>
__global__ void agg_kernel(const __hip_fp8_e4m3* __restrict__ t8, const int* __restrict__ deg,
                           const ushort* __restrict__ ell, __half* __restrict__ uout,
                           const int* __restrict__ batch, float* __restrict__ pooled,
                           float* __restrict__ cntg) {
    __shared__ float rs[4][64];
    __shared__ int gs[4];
    int widx = threadIdx.x >> 6;
    int lane = threadIdx.x & 63;
    int node = blockIdx.x * 4 + widx;
    if (node >= N_NODES) return;   // never taken when POOL (50000 % 4 == 0)
    bool lo = lane < 32;
    int d2 = lane & 31;
    int dt = deg[node];
    int d = min(dt, ELL_CAP);
    int id = (lane < d) ? (int)ell[node * ELL_CAP + lane] : 0;
    const ushort* t2 = (const ushort*)t8;   // row stride 32 ushorts (64B)

    float ax = 0.f, ay = 0.f;
    int e = 0;
    for (; e + 16 <= d; e += 16) {   // 16 edges, 8 wave-loads, 16 line reqs
        int sA0 = __shfl(id, e,      64), sB0 = __shfl(id, e + 1,  64);
        int sA1 = __shfl(id, e + 2,  64), sB1 = __shfl(id, e + 3,  64);
        int sA2 = __shfl(id, e + 4,  64), sB2 = __shfl(id, e + 5,  64);
        int sA3 = __shfl(id, e + 6,  64), sB3 = __shfl(id, e + 7,  64);
        int sA4 = __shfl(id, e + 8,  64), sB4 = __shfl(id, e + 9,  64);
        int sA5 = __shfl(id, e + 10, 64), sB5 = __shfl(id, e + 11, 64);
        int sA6 = __shfl(id, e + 12, 64), sB6 = __shfl(id, e + 13, 64);
        int sA7 = __shfl(id, e + 14, 64), sB7 = __shfl(id, e + 15, 64);
        int s0 = lo ? sA0 : sB0;
        int s1 = lo ? sA1 : sB1;
        int s2 = lo ? sA2 : sB2;
        int s3 = lo ? sA3 : sB3;
        int s4 = lo ? sA4 : sB4;
        int s5 = lo ? sA5 : sB5;
        int s6 = lo ? sA6 : sB6;
        int s7 = lo ? sA7 : sB7;
        ushort w0 = t2[s0 * 32 + d2];
        ushort w1 = t2[s1 * 32 + d2];
        ushort w2 = t2[s2 * 32 + d2];
        ushort w3 = t2[s3 * 32 + d2];
        ushort w4 = t2[s4 * 32 + d2];
        ushort w5 = t2[s5 * 32 + d2];
        ushort w6 = t2[s6 * 32 + d2];
        ushort w7 = t2[s7 * 32 + d2];
        float2 f0 = fp8x2_to_f2(w0);
        float2 f1 = fp8x2_to_f2(w1);
        float2 f2 = fp8x2_to_f2(w2);
        float2 f3 = fp8x2_to_f2(w3);
        float2 f4 = fp8x2_to_f2(w4);
        float2 f5 = fp8x2_to_f2(w5);
        float2 f6 = fp8x2_to_f2(w6);
        float2 f7 = fp8x2_to_f2(w7);
        ax += ((f0.x + f1.x) + (f2.x + f3.x)) + ((f4.x + f5.x) + (f6.x + f7.x));
        ay += ((f0.y + f1.y) + (f2.y + f3.y)) + ((f4.y + f5.y) + (f6.y + f7.y));
    }
    if (e + 8 <= d) {
        int sA0 = __shfl(id, e,     64), sB0 = __shfl(id, e + 1, 64);
        int sA1 = __shfl(id, e + 2, 64), sB1 = __shfl(id, e + 3, 64);
        int sA2 = __shfl(id, e + 4, 64), sB2 = __shfl(id, e + 5, 64);
        int sA3 = __shfl(id, e + 6, 64), sB3 = __shfl(id, e + 7, 64);
        int s0 = lo ? sA0 : sB0;
        int s1 = lo ? sA1 : sB1;
        int s2 = lo ? sA2 : sB2;
        int s3 = lo ? sA3 : sB3;
        float2 f0 = fp8x2_to_f2(t2[s0 * 32 + d2]);
        float2 f1 = fp8x2_to_f2(t2[s1 * 32 + d2]);
        float2 f2 = fp8x2_to_f2(t2[s2 * 32 + d2]);
        float2 f3 = fp8x2_to_f2(t2[s3 * 32 + d2]);
        ax += (f0.x + f1.x) + (f2.x + f3.x);
        ay += (f0.y + f1.y) + (f2.y + f3.y);
        e += 8;
    }
    for (; e + 2 <= d; e += 2) {
        int sA = __shfl(id, e, 64), sB = __shfl(id, e + 1, 64);
        int s = lo ? sA : sB;
        float2 f = fp8x2_to_f2(t2[s * 32 + d2]);
        ax += f.x; ay += f.y;
    }
    if (e < d) {
        int s = __shfl(id, e, 64);
        if (lo) {
            float2 f = fp8x2_to_f2(t2[s * 32 + d2]);
            ax += f.x; ay += f.y;
        }
    }
    ax += __shfl_xor(ax, 32, 64);
    ay += __shfl_xor(ay, 32, 64);

    // mean; the /T8SCALE undoes the fp8 table pre-scale (free)
    float inv = 1.0f / (T8SCALE * fmaxf((float)dt, 1.0f));
    float mx = ax * inv, my = ay * inv;
    if (ACT) {
        mx = (mx >= 0.f) ? mx : 0.2f * mx;
        my = (my >= 0.f) ? my : 0.2f * my;
    }
    float n = sqrtf(reduce32(mx * mx + my * my));
    float sc = (n > TCLIP) ? (TCLIP / n) : 1.0f;
    float rx = mx * sc, ry = my * sc;

    if (POOL) {
        int g = min(max(batch[node], 0), N_GRAPHS - 1);
        if (lo) { rs[widx][2 * d2] = rx; rs[widx][2 * d2 + 1] = ry; }
        if (lane == 0) gs[widx] = g;
        __syncthreads();
        int g0 = gs[0], g1 = gs[1], g2 = gs[2], g3 = gs[3];
        bool uni = (g0 == g1) && (g1 == g2) && (g2 == g3);
        if (uni) {
            if (widx == 0) {
                float sum = rs[0][lane] + rs[1][lane] + rs[2][lane] + rs[3][lane];
                atomicAdd(&pooled[g0 * 64 + lane], sum);
                if (lane == 0) atomicAdd(&cntg[g0], 4.0f);
            }
        } else {
            if (lo) {
                atomicAdd(&pooled[g * 64 + 2 * d2], rx);
                atomicAdd(&pooled[g * 64 + 2 * d2 + 1], ry);
            }
            if (lane == 0) atomicAdd(&cntg[g], 1.0f);
        }
    } else {
        if (lo) ((__half2*)uout)[node * 32 + d2] = __floats2half2_rn(rx, ry);
    }
}

// final head: mean -> clip -> @Wl + bl -> expmap0 -> proj (literal output)
__global__ void head_kernel(const float* __restrict__ pooled, const float* __restrict__ cntg,
                            const float* __restrict__ Wl, const float* __restrict__ bl,
                            float* __restrict__ out) {
    int g = blockIdx.x;
    int lane = threadIdx.x;
    float m = pooled[g * 64 + lane] / fmaxf(cntg[g], 1.0f);
    float z = epl_clip64(m);
    float acc = 0.0f;
    #pragma unroll
    for (int k = 0; k < 64; ++k) {
        float zk = __shfl(z, k, 64);
        if (lane < D_OUT) acc = fmaf(zk, Wl[k * D_OUT + lane], acc);
    }
    float o = (lane < D_OUT) ? (acc + bl[lane]) : 0.0f;
    float n = fmaxf(sqrtf(wave_reduce_sum(o * o)), EPS);
    float v = tanhf(n) * o / n;
    float nv = fmaxf(sqrtf(wave_reduce_sum(v * v)), EPS);
    if (nv > MAX_NORM) v = v * (MAX_NORM / nv);
    if (lane < D_OUT) out[g * D_OUT + lane] = v;
}

// ---------------- launch ----------------

extern "C" void kernel_launch(void* const* d_in, const int* in_sizes, int n_in,
                              void* d_out, int out_size, void* d_ws, size_t ws_size,
                              hipStream_t stream) {
    const float* x   = (const float*)d_in[0];
    const int* edge  = (const int*)d_in[1];
    const int* batch = (const int*)d_in[2];
    const float* W1  = (const float*)d_in[3];
    const float* b1  = (const float*)d_in[4];
    const float* W2  = (const float*)d_in[5];
    const float* b2  = (const float*)d_in[6];
    const float* W3  = (const float*)d_in[7];
    const float* b3  = (const float*)d_in[8];
    const float* Wl  = (const float*)d_in[9];
    const float* bl  = (const float*)d_in[10];
    float* out = (float*)d_out;

    const int N = N_NODES, E = N_EDGES, G = N_GRAPHS;
    const int* src = edge;
    const int* dst = edge + E;

    // ws layout: [deg][pooled][cntg][ell][u0h N*32 h][u1h N*64 h][u2h N*64 h]
    //            [t8 N*64 fp8][m0h N*32 h][Wh1][Wh2][Wh3]
    // transient build aliases: sorted (4.8MB) -> u2h region (6.4MB),
    //                          rowOffs (1.6MB) -> t8 region (3.2MB);
    // both regions are only written by later-stage kernels (agg L2 / gemm L2).
    char* ws = (char*)d_ws;
    int*    deg    = (int*)ws;
    float*  pooled = (float*)(deg + N);
    float*  cntg   = pooled + (size_t)G * 64;
    ushort* ell    = (ushort*)(cntg + G);
    __half* u0h    = (__half*)(ell + (size_t)N * ELL_CAP);
    __half* u1h    = u0h + (size_t)N * 32;
    __half* u2h    = u1h + (size_t)N * 64;
    __hip_fp8_e4m3* t8 = (__hip_fp8_e4m3*)(u2h + (size_t)N * 64);
    __half* m0h    = (__half*)((char*)t8 + (size_t)N * 64);
    __half* Wh1    = m0h + (size_t)N * 32;    // 2048
    __half* Wh2    = Wh1 + 2048;              // 4096
    __half* Wh3    = Wh2 + 4096;              // 4096

    unsigned* sortedbuf = (unsigned*)u2h;     // HB*CHUNK u32 = 4.8MB <= 6.4MB
    int*      rowOffs   = (int*)t8;           // HB*(NBUCK+1) = 1.6MB <= 3.2MB

    // deg is fully overwritten by ellbuild; only pooling accumulators need 0.
    hipMemsetAsync(pooled, 0, ((size_t)G * 64 + G) * 4, stream);

    int blocksN64 = (N * 64 + 255) / 256;   // one wave per node, 4 per block
    int blocksG   = 3125;                   // layers 2,3 gemm (jb split)
    int blocksT   = (3125 + 3) / 4;         // gemmepi: one wave per 16-node tile

    repack_kernel<32><<<8,  256, 0, stream>>>(W1, Wh1);
    repack_kernel<64><<<16, 256, 0, stream>>>(W2, Wh2);
    repack_kernel<64><<<16, 256, 0, stream>>>(W3, Wh3);

    // atomic-free ELL build: local bucket-partition, then per-bucket build
    partsort_kernel<<<HB + blocksN64, 256, 0, stream>>>(src, dst, sortedbuf, rowOffs, x, u0h);
    ellbuild_kernel<<<NBUCK, 256, 0, stream>>>(sortedbuf, rowOffs, deg, ell);

    // layer 1: gather-mean u0 (L2-resident, 1 line/edge) -> MFMA+epi
    meangather_kernel<<<blocksN64, 256, 0, stream>>>(u0h, deg, ell, m0h);
    gemmepi_kernel<<<blocksT, 256, 0, stream>>>(m0h, Wh1, b1, deg, u1h);

    // layer 2: fp8 table (1 line/edge gather)
    gemm_kernel<64><<<blocksG, 256, 0, stream>>>(u1h, Wh2, b2, t8);
    agg_kernel<1, 0><<<blocksN64, 256, 0, stream>>>(t8, deg, ell, u2h, nullptr, nullptr, nullptr);
    // layer 3 (no act) + LDS-combined pooling
    gemm_kernel<64><<<blocksG, 256, 0, stream>>>(u2h, Wh3, b3, t8);
    agg_kernel<0, 1><<<blocksN64, 256, 0, stream>>>(t8, deg, ell, nullptr, batch, pooled, cntg);

    head_kernel<<<G, 64, 0, stream>>>(pooled, cntg, Wl, bl, out);
}

// Round 2
// 267.126 us; speedup vs baseline: 1.2758x; 1.0176x over previous
//
#include <hip/hip_runtime.h>
#include <hip/hip_fp16.h>
#include <hip/hip_fp8.h>
#include <math.h>

#define N_NODES 50000
#define N_EDGES 1200000
#define N_GRAPHS 128
#define D_IN 32
#define D_H 64
#define D_OUT 10
#define ELL_CAP 64

#define EPS 1e-7f
#define MAX_NORM (1.0f - 1e-5f)
// atanh(MAX_NORM): logmap0(proj(expmap0(m))) == m * min(1, TCLIP/||m||)
#define TCLIP 6.1030335f
#define T8SCALE 16.0f            // fp8 table pre-scale (folded into mean div)

// ---- atomic-free ELL build: counting partition ----
#define HB 512                               // partition blocks (chunks)
#define CHUNK ((N_EDGES + HB - 1) / HB)      // 2344 edges per chunk
#define NBUCK ((N_NODES + 63) / 64)          // 782 buckets of 64 nodes

typedef _Float16 half8 __attribute__((ext_vector_type(8)));
typedef float float4v __attribute__((ext_vector_type(4)));

// ---------------- wave helpers ----------------

__device__ __forceinline__ float wave_reduce_sum(float v) {
    #pragma unroll
    for (int off = 32; off > 0; off >>= 1)
        v += __shfl_xor(v, off, 64);
    return v;
}

// logmap0(proj(expmap0(m))) collapsed to a norm clip (one reduction).
__device__ __forceinline__ float epl_clip64(float m) {
    float n = sqrtf(wave_reduce_sum(m * m));
    float sc = (n > TCLIP) ? (TCLIP / n) : 1.0f;
    return m * sc;
}

// two packed OCP e4m3 bytes -> two floats (gfx950 HW cvt)
__device__ __forceinline__ float2 fp8x2_to_f2(ushort v) {
    __hip_fp8_e4m3 a, b;
    a.__x = (__hip_fp8_storage_t)(v & 0xff);
    b.__x = (__hip_fp8_storage_t)(v >> 8);
    return make_float2((float)a, (float)b);
}

// ---------------- kernels ----------------

// Partition pass: blocks [0,HB) bucket-sort their edge chunk locally
// (LDS histogram + scan + LDS-atomic rank; all global writes coalesced
// into the block's own window -> full write combining, NO global atomics).
// Blocks [HB..): tangent0 = fp16(clip(x)) (unchanged u0 computation).
__global__ void partsort_kernel(const int* __restrict__ src, const int* __restrict__ dst,
                                unsigned* __restrict__ sorted, int* __restrict__ rowOffs,
                                const float* __restrict__ x, __half* __restrict__ u0) {
    __shared__ int hist[1024];   // NBUCK=782 padded to 4*256
    __shared__ int wsum[256];
    if (blockIdx.x >= HB) {
        int gid = (blockIdx.x - HB) * 256 + threadIdx.x;
        int node = gid >> 6;
        int lane = gid & 63;
        if (node >= N_NODES) return;
        float m = (lane < D_IN) ? x[node * D_IN + lane] : 0.0f;
        float t = epl_clip64(m);
        if (lane < D_IN) u0[node * D_IN + lane] = __float2half(t);
        return;
    }
    int i = blockIdx.x;
    int e0 = i * CHUNK;
    int e1 = min(e0 + CHUNK, N_EDGES);

    for (int t = threadIdx.x; t < 1024; t += 256) hist[t] = 0;
    __syncthreads();
    // pass 1: bucket histogram (LDS atomics only)
    for (int e = e0 + threadIdx.x; e < e1; e += 256) {
        int d = dst[e];
        d = min(max(d, 0), N_NODES - 1);
        atomicAdd(&hist[d >> 6], 1);
    }
    __syncthreads();
    // exclusive scan of hist[0..1023]: 4 elems/thread + block scan of sums
    int t = threadIdx.x;
    int a0 = hist[4 * t], a1 = hist[4 * t + 1], a2 = hist[4 * t + 2], a3 = hist[4 * t + 3];
    int s01 = a0 + a1;
    int s = s01 + a2 + a3;
    wsum[t] = s;
    __syncthreads();
    for (int off = 1; off < 256; off <<= 1) {
        int v = (t >= off) ? wsum[t - off] : 0;
        __syncthreads();
        wsum[t] += v;
        __syncthreads();
    }
    int base = wsum[t] - s;      // exclusive prefix of this thread's 4
    hist[4 * t]     = base;
    hist[4 * t + 1] = base + a0;
    hist[4 * t + 2] = base + s01;
    hist[4 * t + 3] = base + s01 + a2;
    __syncthreads();
    // publish per-(chunk,bucket) offsets; row-major -> coalesced writes.
    // hist[NBUCK] == chunk length (buckets >= NBUCK are empty).
    for (int jj = threadIdx.x; jj <= NBUCK; jj += 256)
        rowOffs[i * (NBUCK + 1) + jj] = hist[jj];
    __syncthreads();
    // pass 2: rank via LDS atomic on the scanned cursors, write packed edge
    // into this block's own CHUNK-sized window (stays in one L2, combines).
    for (int e = e0 + threadIdx.x; e < e1; e += 256) {
        int s_ = src[e];
        int d  = dst[e];
        s_ = min(max(s_, 0), N_NODES - 1);
        d  = min(max(d,  0), N_NODES - 1);
        int pos = atomicAdd(&hist[d >> 6], 1);
        sorted[(size_t)i * CHUNK + pos] = ((unsigned)d << 16) | (unsigned)s_;
    }
}

// ELL build: one block per 64-node bucket. Gathers this bucket's runs from
// all HB chunk windows; ranks with LDS atomics; ELL writes land in the
// block's own contiguous 16KB region (perfect write combining). Exact deg
// falls out of the counters -> no deg memset needed.
__global__ void ellbuild_kernel(const unsigned* __restrict__ sorted, const int* __restrict__ rowOffs,
                                int* __restrict__ deg, ushort* __restrict__ ell) {
    __shared__ int cnt[64];
    int j = blockIdx.x;
    if (threadIdx.x < 64) cnt[threadIdx.x] = 0;
    __syncthreads();
    for (int i = threadIdx.x; i < HB; i += 256) {
        int b0 = rowOffs[i * (NBUCK + 1) + j];
        int b1 = rowOffs[i * (NBUCK + 1) + j + 1];
        const unsigned* sp = sorted + (size_t)i * CHUNK;
        for (int e = b0; e < b1; ++e) {
            unsigned p = sp[e];
            int dl = (int)(p >> 16) & 63;
            int pos = atomicAdd(&cnt[dl], 1);
            if (pos < ELL_CAP)
                ell[(size_t)((j << 6) + dl) * ELL_CAP + pos] = (ushort)(p & 0xffffu);
        }
    }
    __syncthreads();
    int node = (j << 6) + threadIdx.x;
    if (threadIdx.x < 64 && node < N_NODES) deg[node] = cnt[threadIdx.x];
}

// Repack W (f32 [K,64]) into B-fragment order for mfma_f32_16x16x32_f16.
template <int K>
__global__ void repack_kernel(const float* __restrict__ W, __half* __restrict__ Whf) {
    const int NF = K / 32;
    int idx = blockIdx.x * 256 + threadIdx.x;
    if (idx >= 4 * NF * 64 * 8) return;
    int j = idx & 7;
    int lane = (idx >> 3) & 63;
    int f = (idx >> 9) % NF;
    int jb = (idx >> 9) / NF;
    int k = f * 32 + ((lane >> 4) * 8) + j;
    int n = jb * 16 + (lane & 15);
    Whf[idx] = __float2half(W[k * 64 + n]);
}

// LAYER 1 pass A: gather-mean of u0 rows (32-dim fp16 = 64B = 1 line/edge,
// 3.2MB L2-resident). 8 lanes per row, uint2/lane: 8 edges (8 lines) per
// wave-load; all batches issued before first use (deep MLP).
__global__ void meangather_kernel(const __half* __restrict__ u0, const int* __restrict__ deg,
                                  const ushort* __restrict__ ell, __half* __restrict__ m0) {
    int widx = threadIdx.x >> 6;
    int lane = threadIdx.x & 63;
    int node = blockIdx.x * 4 + widx;
    if (node >= N_NODES) return;
    int g = lane >> 3;          // edge group 0..7
    int d8 = lane & 7;          // dim slice: halfs d8*4 .. d8*4+3
    int dt = deg[node];
    int d = min(dt, ELL_CAP);
    int id = (lane < d) ? (int)ell[node * ELL_CAP + lane] : 0;
    const char* base = (const char*)u0;

    int sidx[8];
    #pragma unroll
    for (int i = 0; i < 8; ++i)
        sidx[i] = __shfl(id, i * 8 + g, 64);

    uint2 v[8];
    #pragma unroll
    for (int i = 0; i < 8; ++i)
        if (i * 8 < d)          // wave-uniform
            v[i] = *(const uint2*)(base + ((size_t)sidx[i] << 6) + (d8 << 3));

    float a0 = 0.f, a1 = 0.f, a2 = 0.f, a3 = 0.f;
    #pragma unroll
    for (int i = 0; i < 8; ++i) {
        if (i * 8 < d) {
            float w = ((i * 8 + g) < d) ? 1.0f : 0.0f;
            float2 f0 = __half22float2(*reinterpret_cast<const __half2*>(&v[i].x));
            float2 f1 = __half22float2(*reinterpret_cast<const __half2*>(&v[i].y));
            a0 = fmaf(f0.x, w, a0);
            a1 = fmaf(f0.y, w, a1);
            a2 = fmaf(f1.x, w, a2);
            a3 = fmaf(f1.y, w, a3);
        }
    }
    // reduce across the 8 edge-groups (lane bits 3..5)
    #pragma unroll
    for (int off = 8; off <= 32; off <<= 1) {
        a0 += __shfl_xor(a0, off, 64);
        a1 += __shfl_xor(a1, off, 64);
        a2 += __shfl_xor(a2, off, 64);
        a3 += __shfl_xor(a3, off, 64);
    }
    float inv = 1.0f / fmaxf((float)dt, 1.0f);
    if (g == 0) {
        __half2 h0 = __floats2half2_rn(a0 * inv, a1 * inv);
        __half2 h1 = __floats2half2_rn(a2 * inv, a3 * inv);
        uint2 pk;
        pk.x = *reinterpret_cast<uint*>(&h0);
        pk.y = *reinterpret_cast<uint*>(&h1);
        *(uint2*)((char*)m0 + ((size_t)node << 6) + (d8 << 3)) = pk;
    }
}

// LAYER 1 pass B: u1 = clip(lrelu(m0@W1 + b1)), deg==0 -> 0.
__global__ void gemmepi_kernel(const __half* __restrict__ m0, const __half* __restrict__ Whf,
                               const float* __restrict__ b, const int* __restrict__ deg,
                               __half* __restrict__ uout) {
    int gw = blockIdx.x * 4 + (threadIdx.x >> 6);
    int lane = threadIdx.x & 63;
    int node0 = gw * 16;
    if (node0 >= N_NODES) return;
    int m = lane & 15, quad = lane >> 4;

    half8 a = *(const half8*)(m0 + (size_t)(node0 + m) * 32 + quad * 8);
    float h[4][4];   // [jb][r]
    #pragma unroll
    for (int jb = 0; jb < 4; ++jb) {
        float4v acc = {0.f, 0.f, 0.f, 0.f};
        half8 bb = ((const half8*)Whf)[jb * 64 + lane];
        acc = __builtin_amdgcn_mfma_f32_16x16x32_f16(a, bb, acc, 0, 0, 0);
        float bias = b[jb * 16 + m];
        #pragma unroll
        for (int r = 0; r < 4; ++r) h[jb][r] = acc[r] + bias;
    }
    #pragma unroll
    for (int r = 0; r < 4; ++r) {
        int node = node0 + quad * 4 + r;   // C/D: col=lane&15, row=quad*4+reg
        int dt = deg[node];
        float nr = 0.f;
        #pragma unroll
        for (int jb = 0; jb < 4; ++jb) {
            float v = (dt == 0) ? 0.f : h[jb][r];
            v = (v >= 0.f) ? v : 0.2f * v;   // leaky_relu (layer 1)
            h[jb][r] = v;
            nr += v * v;
        }
        nr += __shfl_xor(nr, 1, 64); nr += __shfl_xor(nr, 2, 64);
        nr += __shfl_xor(nr, 4, 64); nr += __shfl_xor(nr, 8, 64);
        float n = sqrtf(nr);
        float sc = (n > TCLIP) ? (TCLIP / n) : 1.0f;
        #pragma unroll
        for (int jb = 0; jb < 4; ++jb)
            uout[node * 64 + jb * 16 + m] = __float2half(h[jb][r] * sc);
    }
}

// t[N,64] fp8 e4m3 (x16 scale) = u[N,K] fp16 @ W + b via MFMA (layers 2,3).
// fp8 rows are 64B = ONE line per edge-gather.
template <int K>
__global__ void gemm_kernel(const __half* __restrict__ u, const __half* __restrict__ Whf,
                            const float* __restrict__ b, __hip_fp8_e4m3* __restrict__ t8) {
    const int NF = K / 32;
    int gw = blockIdx.x * 4 + (threadIdx.x >> 6);
    int lane = threadIdx.x & 63;
    int jb = gw & 3;
    int tile = gw >> 2;
    int node0 = tile * 16;
    if (node0 >= N_NODES) return;
    int m = lane & 15, quad = lane >> 4;

    float4v acc = {0.f, 0.f, 0.f, 0.f};
    const half8* bfr = (const half8*)Whf + (size_t)(jb * NF) * 64 + lane;
    #pragma unroll
    for (int f = 0; f < NF; ++f) {
        half8 a = *(const half8*)(u + (size_t)(node0 + m) * K + f * 32 + quad * 8);
        half8 bb = bfr[f * 64];
        acc = __builtin_amdgcn_mfma_f32_16x16x32_f16(a, bb, acc, 0, 0, 0);
    }
    int j = jb * 16 + m;
    float bias = b[j];
    #pragma unroll
    for (int r = 0; r < 4; ++r) {
        int node = node0 + quad * 4 + r;
        t8[node * 64 + j] = __hip_fp8_e4m3((acc[r] + bias) * T8SCALE);
    }
}

// Gather-mean over ELL (fp8 rows, 64B = 1 line/edge). 8 lanes per row,
// uint2/lane: 8 edges (8 lines) per wave-load, all batches issued before
// first use -> deep MLP. Then act -> norm-clip -> fp16 store, or (POOL)
// block LDS combine + 1 atomic burst per block. (layers 2,3)
template <int ACT, int POOL>
__global__ void agg_kernel(const __hip_fp8_e4m3* __restrict__ t8, const int* __restrict__ deg,
                           const ushort* __restrict__ ell, __half* __restrict__ uout,
                           const int* __restrict__ batch, float* __restrict__ pooled,
                           float* __restrict__ cntg) {
    __shared__ float rs[4][64];
    __shared__ int gs[4];
    int widx = threadIdx.x >> 6;
    int lane = threadIdx.x & 63;
    int node = blockIdx.x * 4 + widx;
    if (node >= N_NODES) return;   // never taken when POOL (50000 % 4 == 0)
    int g = lane >> 3;          // edge group 0..7
    int d8 = lane & 7;          // dim slice: dims d8*8 .. d8*8+7
    int dt = deg[node];
    int d = min(dt, ELL_CAP);
    int id = (lane < d) ? (int)ell[node * ELL_CAP + lane] : 0;
    const char* base = (const char*)t8;

    int sidx[8];
    #pragma unroll
    for (int i = 0; i < 8; ++i)
        sidx[i] = __shfl(id, i * 8 + g, 64);

    uint2 v[8];
    #pragma unroll
    for (int i = 0; i < 8; ++i)
        if (i * 8 < d)          // wave-uniform
            v[i] = *(const uint2*)(base + ((size_t)sidx[i] << 6) + (d8 << 3));

    float acc[8] = {0.f, 0.f, 0.f, 0.f, 0.f, 0.f, 0.f, 0.f};
    #pragma unroll
    for (int i = 0; i < 8; ++i) {
        if (i * 8 < d) {
            float w = ((i * 8 + g) < d) ? 1.0f : 0.0f;
            uint lo_ = v[i].x, hi_ = v[i].y;
            float2 f0 = fp8x2_to_f2((ushort)(lo_ & 0xffffu));
            float2 f1 = fp8x2_to_f2((ushort)(lo_ >> 16));
            float2 f2 = fp8x2_to_f2((ushort)(hi_ & 0xffffu));
            float2 f3 = fp8x2_to_f2((ushort)(hi_ >> 16));
            acc[0] = fmaf(f0.x, w, acc[0]);
            acc[1] = fmaf(f0.y, w, acc[1]);
            acc[2] = fmaf(f1.x, w, acc[2]);
            acc[3] = fmaf(f1.y, w, acc[3]);
            acc[4] = fmaf(f2.x, w, acc[4]);
            acc[5] = fmaf(f2.y, w, acc[5]);
            acc[6] = fmaf(f3.x, w, acc[6]);
            acc[7] = fmaf(f3.y, w, acc[7]);
        }
    }
    // reduce across the 8 edge-groups (lane bits 3..5)
    #pragma unroll
    for (int j = 0; j < 8; ++j) {
        acc[j] += __shfl_xor(acc[j], 8, 64);
        acc[j] += __shfl_xor(acc[j], 16, 64);
        acc[j] += __shfl_xor(acc[j], 32, 64);
    }

    // mean; the /T8SCALE undoes the fp8 table pre-scale (free)
    float inv = 1.0f / (T8SCALE * fmaxf((float)dt, 1.0f));
    float val[8];
    float nr = 0.f;
    #pragma unroll
    for (int j = 0; j < 8; ++j) {
        float m = acc[j] * inv;
        if (ACT) m = (m >= 0.f) ? m : 0.2f * m;
        val[j] = m;
        nr = fmaf(m, m, nr);
    }
    // norm: sum the 8 dim-slices (lane bits 0..2)
    nr += __shfl_xor(nr, 1, 64);
    nr += __shfl_xor(nr, 2, 64);
    nr += __shfl_xor(nr, 4, 64);
    float n = sqrtf(nr);
    float sc = (n > TCLIP) ? (TCLIP / n) : 1.0f;
    #pragma unroll
    for (int j = 0; j < 8; ++j) val[j] *= sc;

    if (POOL) {
        int gi = min(max(batch[node], 0), N_GRAPHS - 1);
        if (g == 0) {
            #pragma unroll
            for (int j = 0; j < 8; ++j) rs[widx][d8 * 8 + j] = val[j];
        }
        if (lane == 0) gs[widx] = gi;
        __syncthreads();
        int g0 = gs[0], g1 = gs[1], g2 = gs[2], g3 = gs[3];
        bool uni = (g0 == g1) && (g1 == g2) && (g2 == g3);
        if (uni) {
            if (widx == 0) {
                float sum = rs[0][lane] + rs[1][lane] + rs[2][lane] + rs[3][lane];
                atomicAdd(&pooled[g0 * 64 + lane], sum);
                if (lane == 0) atomicAdd(&cntg[g0], 4.0f);
            }
        } else {
            if (g == 0) {
                #pragma unroll
                for (int j = 0; j < 8; ++j)
                    atomicAdd(&pooled[gi * 64 + d8 * 8 + j], val[j]);
            }
            if (lane == 0) atomicAdd(&cntg[gi], 1.0f);
        }
    } else {
        if (g == 0) {
            half8 hv;
            #pragma unroll
            for (int j = 0; j < 8; ++j) hv[j] = (_Float16)val[j];
            *(half8*)((char*)uout + ((size_t)node << 7) + (d8 << 4)) = hv;
        }
    }
}

// final head: mean -> clip -> @Wl + bl -> expmap0 -> proj (literal output)
__global__ void head_kernel(const float* __restrict__ pooled, const float* __restrict__ cntg,
                            const float* __restrict__ Wl, const float* __restrict__ bl,
                            float* __restrict__ out) {
    int g = blockIdx.x;
    int lane = threadIdx.x;
    float m = pooled[g * 64 + lane] / fmaxf(cntg[g], 1.0f);
    float z = epl_clip64(m);
    float acc = 0.0f;
    #pragma unroll
    for (int k = 0; k < 64; ++k) {
        float zk = __shfl(z, k, 64);
        if (lane < D_OUT) acc = fmaf(zk, Wl[k * D_OUT + lane], acc);
    }
    float o = (lane < D_OUT) ? (acc + bl[lane]) : 0.0f;
    float n = fmaxf(sqrtf(wave_reduce_sum(o * o)), EPS);
    float v = tanhf(n) * o / n;
    float nv = fmaxf(sqrtf(wave_reduce_sum(v * v)), EPS);
    if (nv > MAX_NORM) v = v * (MAX_NORM / nv);
    if (lane < D_OUT) out[g * D_OUT + lane] = v;
}

// ---------------- launch ----------------

extern "C" void kernel_launch(void* const* d_in, const int* in_sizes, int n_in,
                              void* d_out, int out_size, void* d_ws, size_t ws_size,
                              hipStream_t stream) {
    const float* x   = (const float*)d_in[0];
    const int* edge  = (const int*)d_in[1];
    const int* batch = (const int*)d_in[2];
    const float* W1  = (const float*)d_in[3];
    const float* b1  = (const float*)d_in[4];
    const float* W2  = (const float*)d_in[5];
    const float* b2  = (const float*)d_in[6];
    const float* W3  = (const float*)d_in[7];
    const float* b3  = (const float*)d_in[8];
    const float* Wl  = (const float*)d_in[9];
    const float* bl  = (const float*)d_in[10];
    float* out = (float*)d_out;

    const int N = N_NODES, E = N_EDGES, G = N_GRAPHS;
    const int* src = edge;
    const int* dst = edge + E;

    // ws layout: [deg][pooled][cntg][ell][u0h N*32 h][u1h N*64 h][u2h N*64 h]
    //            [t8 N*64 fp8][m0h N*32 h][Wh1][Wh2][Wh3]
    // transient build aliases: sorted (4.8MB) -> u2h region (6.4MB),
    //                          rowOffs (1.6MB) -> t8 region (3.2MB).
    char* ws = (char*)d_ws;
    int*    deg    = (int*)ws;
    float*  pooled = (float*)(deg + N);
    float*  cntg   = pooled + (size_t)G * 64;
    ushort* ell    = (ushort*)(cntg + G);
    __half* u0h    = (__half*)(ell + (size_t)N * ELL_CAP);
    __half* u1h    = u0h + (size_t)N * 32;
    __half* u2h    = u1h + (size_t)N * 64;
    __hip_fp8_e4m3* t8 = (__hip_fp8_e4m3*)(u2h + (size_t)N * 64);
    __half* m0h    = (__half*)((char*)t8 + (size_t)N * 64);
    __half* Wh1    = m0h + (size_t)N * 32;    // 2048
    __half* Wh2    = Wh1 + 2048;              // 4096
    __half* Wh3    = Wh2 + 4096;              // 4096

    unsigned* sortedbuf = (unsigned*)u2h;     // HB*CHUNK u32 = 4.8MB <= 6.4MB
    int*      rowOffs   = (int*)t8;           // HB*(NBUCK+1) = 1.6MB <= 3.2MB

    // deg is fully overwritten by ellbuild; only pooling accumulators need 0.
    hipMemsetAsync(pooled, 0, ((size_t)G * 64 + G) * 4, stream);

    int blocksN64 = (N * 64 + 255) / 256;   // one wave per node, 4 per block
    int blocksG   = 3125;                   // layers 2,3 gemm (jb split)
    int blocksT   = (3125 + 3) / 4;         // gemmepi: one wave per 16-node tile

    repack_kernel<32><<<8,  256, 0, stream>>>(W1, Wh1);
    repack_kernel<64><<<16, 256, 0, stream>>>(W2, Wh2);
    repack_kernel<64><<<16, 256, 0, stream>>>(W3, Wh3);

    // atomic-free ELL build: local bucket-partition, then per-bucket build
    partsort_kernel<<<HB + blocksN64, 256, 0, stream>>>(src, dst, sortedbuf, rowOffs, x, u0h);
    ellbuild_kernel<<<NBUCK, 256, 0, stream>>>(sortedbuf, rowOffs, deg, ell);

    // layer 1: gather-mean u0 (L2-resident, 1 line/edge) -> MFMA+epi
    meangather_kernel<<<blocksN64, 256, 0, stream>>>(u0h, deg, ell, m0h);
    gemmepi_kernel<<<blocksT, 256, 0, stream>>>(m0h, Wh1, b1, deg, u1h);

    // layer 2: fp8 table (1 line/edge gather)
    gemm_kernel<64><<<blocksG, 256, 0, stream>>>(u1h, Wh2, b2, t8);
    agg_kernel<1, 0><<<blocksN64, 256, 0, stream>>>(t8, deg, ell, u2h, nullptr, nullptr, nullptr);
    // layer 3 (no act) + LDS-combined pooling
    gemm_kernel<64><<<blocksG, 256, 0, stream>>>(u2h, Wh3, b3, t8);
    agg_kernel<0, 1><<<blocksN64, 256, 0, stream>>>(t8, deg, ell, nullptr, batch, pooled, cntg);

    head_kernel<<<G, 64, 0, stream>>>(pooled, cntg, Wl, bl, out);
}